// Round 2
// baseline (158.694 us; speedup 1.0000x reference)
//
#include <hip/hip_runtime.h>
#include <hip/hip_bf16.h>

#define IN_F   4096
#define OUT_F  4096
#define QBLK   8
#define NBLKS  512
#define NTOK   1024
#define NCENT  2048

#define SPLITK 4
#define KCHUNK (IN_F / SPLITK)   // 1024
#define KITERS (KCHUNK / 32)     // 32

typedef unsigned int u32;
typedef unsigned short u16;
typedef __attribute__((ext_vector_type(8))) short short8;   // 8 bf16 (MFMA A/B frag)
typedef __attribute__((ext_vector_type(4))) float floatx4;  // MFMA C/D frag

// round-to-nearest-even fp32 -> bf16
__device__ __forceinline__ u16 f2bf(float f) {
  union { float f; u32 u; } v; v.f = f;
  u32 u = v.u;
  return (u16)((u + 0x7fffu + ((u >> 16) & 1u)) >> 16);
}

__device__ __forceinline__ void load_lds_16(const void* g, void* l) {
  __builtin_amdgcn_global_load_lds(
      (const __attribute__((address_space(1))) u32*)g,
      (__attribute__((address_space(3))) u32*)l, 16, 0, 0);
}

// ---------------------------------------------------------------------------
// zero-fill out (atomic split-K accumulates into it)
// ---------------------------------------------------------------------------
__global__ __launch_bounds__(256) void zero_kernel(float* __restrict__ p) {
  int g = blockIdx.x * 256 + threadIdx.x;
  ((float4*)p)[g] = make_float4(0.f, 0.f, 0.f, 0.f);
}

// ---------------------------------------------------------------------------
// cast fp32 -> bf16 (plain layout) -- used for centroids only
// ---------------------------------------------------------------------------
__global__ __launch_bounds__(256) void cast_bf16_kernel(
    const float* __restrict__ src, u16* __restrict__ dst) {
  int g = blockIdx.x * 256 + threadIdx.x;   // one 8-element chunk
  const float4* sv = (const float4*)src;
  float4 a = sv[(size_t)g * 2];
  float4 b = sv[(size_t)g * 2 + 1];
  union { u16 s[8]; uint4 v; } o;
  o.s[0] = f2bf(a.x); o.s[1] = f2bf(a.y); o.s[2] = f2bf(a.z); o.s[3] = f2bf(a.w);
  o.s[4] = f2bf(b.x); o.s[5] = f2bf(b.y); o.s[6] = f2bf(b.z); o.s[7] = f2bf(b.w);
  ((uint4*)dst)[g] = o.v;
}

// ---------------------------------------------------------------------------
// cast x fp32 -> bf16 in MFMA-fragment-ordered layout:
//   elem (m,k) -> [(m>>4)*512 + (k>>3)]*128 + (m&15)*8 + (k&7)
// A wave's A-fragment load becomes ONE contiguous 1 KB global_load_dwordx4.
// ---------------------------------------------------------------------------
__global__ __launch_bounds__(256) void cast_swz_kernel(
    const float* __restrict__ src, u16* __restrict__ dst) {
  __shared__ __align__(16) u16 ls[256 * 8];      // 256 chunks of 16 B = 4 KB
  const int b = blockIdx.x;
  const int mg = b >> 5;          // m-group 0..63
  const int kq = b & 31;          // k-chunk of 128 elems, 0..31
  const int t = threadIdx.x;
  const int ml = t >> 4;          // m within group 0..15
  const int kbl = t & 15;         // quant block within chunk 0..15

  const float* p = src + (size_t)(mg * 16 + ml) * IN_F + kq * 128 + kbl * 8;
  float4 a = ((const float4*)p)[0];
  float4 c = ((const float4*)p)[1];
  union { u16 s[8]; uint4 v; } o;
  o.s[0] = f2bf(a.x); o.s[1] = f2bf(a.y); o.s[2] = f2bf(a.z); o.s[3] = f2bf(a.w);
  o.s[4] = f2bf(c.x); o.s[5] = f2bf(c.y); o.s[6] = f2bf(c.z); o.s[7] = f2bf(c.w);

  const int cidx = (kbl << 4) | (ml ^ kbl);      // bank-spread slot
  *(uint4*)&ls[cidx * 8] = o.v;
  __syncthreads();

  const int g = (t & 0xF0) | ((t & 15) ^ ((t >> 4) & 15));
  uint4* dbase = (uint4*)(dst + (size_t)(mg * 512 + kq * 16) * 128);
  dbase[g] = ((const uint4*)ls)[t];
}

// ---------------------------------------------------------------------------
// Fused GEMM, barrier-free K-loop, atomic split-K epilogue.
//   C[m][n] = sum_k x[m][k] * centroids[assign[(k/8)*OUT_F+n]][k%8]
// Block tile 128x128, 4 waves (2x2) each 64x64 (4x4 of mfma_f32_16x16x32_bf16).
// A fragments: direct coalesced 1KB global loads from fragment-ordered xs,
// register double-buffered one iter ahead. Addressing is 32-bit: the per-lane
// component of the A address (quad*256+r16*16) and idx address (quad*OUT_F+
// ncol) are each ONE u32 VGPR; everything else is uniform (SGPR). Total regs
// (VGPR + 64 acc AGPR) <= 128 -> 4 waves/SIMD.
// B fragments: gathered from the read-only 32 KB bf16 centroid table in LDS.
// Split-K over blockIdx.z; all chunks unsafeAtomicAdd into zero-filled out
// (s==0 adds bias) -- no partials buffer, no reduce pass.
// ---------------------------------------------------------------------------
__global__ __launch_bounds__(256, 4) void gemm_fused_kernel(
    const u16* __restrict__ xs,     // x bf16, fragment-ordered [64][512][16][8]
    const u16* __restrict__ centb,  // [NCENT][8] bf16
    const int* __restrict__ assign, // [NBLKS*OUT_F] block-major
    const float* __restrict__ bias,
    float* __restrict__ out) {      // zero-filled, atomically accumulated
  __shared__ __align__(16) u16 cs[NCENT * 8];   // 32 KB centroid table

  const int t = threadIdx.x;
  const int lane = t & 63;
  const int wv = t >> 6;
  const int wm = wv >> 1;
  const int wn = wv & 1;
  const int quad = lane >> 4;
  const int r16 = lane & 15;
  const int m0 = blockIdx.y * 128;
  const int n0 = blockIdx.x * 128;
  const int s = blockIdx.z;
  const int kb0 = (s * KCHUNK) >> 3;       // first quant block of this chunk

  // stage centroid table: 2048 chunks of 16B = 8 per thread (DMA, no VGPR)
#pragma unroll
  for (int it = 0; it < 8; ++it) {
    int c = it * 256 + t;
    load_lds_16(centb + (size_t)c * 8, cs + (size_t)c * 8);
  }

  floatx4 acc[4][4];
#pragma unroll
  for (int i = 0; i < 4; ++i)
#pragma unroll
    for (int j = 0; j < 4; ++j)
#pragma unroll
      for (int r = 0; r < 4; ++r) acc[i][j][r] = 0.0f;

  const int ncol = n0 + wn * 64 + r16;

  // A: uniform base (SGPR) + one per-lane u32 byte offset.
  // short8 index was ((m>>4)*512 + kb)*16 + (m&15); in bytes x16.
  const char* xA = (const char*)xs +
      ((size_t)((m0 >> 4) + wm * 4) * 512 + kb0) * 256;  // uniform
  const u32 va = (u32)(quad * 256 + r16 * 16);           // per-lane bytes
  // idx: uniform base + one per-lane u32 element offset
  const int* ai = assign + (size_t)kb0 * OUT_F;          // uniform
  const u32 vi = (u32)(quad * OUT_F + ncol);             // per-lane elems

  // prologue: load iter-0 A frags + indices
  short8 afc[4];
  int idxc[4];
#pragma unroll
  for (int i = 0; i < 4; ++i)
    afc[i] = *(const short8*)(xA + (va + (u32)i * 131072u));
#pragma unroll
  for (int j = 0; j < 4; ++j) idxc[j] = ai[vi + (u32)(j * 16)];

  __syncthreads();   // centroid table ready (single barrier of the kernel)

  const short8* csv = (const short8*)cs;
#pragma unroll 2
  for (int kt = 0; kt < KITERS; ++kt) {
    // prefetch next iteration's A frags + indices (uniform guard)
    short8 afn[4];
    int idxn[4];
    if (kt + 1 < KITERS) {
      const char* xk = xA + (va + (u32)((kt + 1) * 1024));
#pragma unroll
      for (int i = 0; i < 4; ++i)
        afn[i] = *(const short8*)(xk + (u32)i * 131072u);
      const int* an = ai + (size_t)(kt + 1) * 4 * OUT_F;
#pragma unroll
      for (int j = 0; j < 4; ++j) idxn[j] = an[vi + (u32)(j * 16)];
    }

    // gather B frags from LDS table (one 16 B lookup per lane per frag)
    short8 bfr[4];
#pragma unroll
    for (int j = 0; j < 4; ++j) bfr[j] = csv[idxc[j]];

#pragma unroll
    for (int i = 0; i < 4; ++i)
#pragma unroll
      for (int j = 0; j < 4; ++j)
        acc[i][j] = __builtin_amdgcn_mfma_f32_16x16x32_bf16(afc[i], bfr[j], acc[i][j], 0, 0, 0);

#pragma unroll
    for (int i = 0; i < 4; ++i) afc[i] = afn[i];
#pragma unroll
    for (int j = 0; j < 4; ++j) idxc[j] = idxn[j];
  }

  // epilogue: C/D layout col = lane&15 (+j*16), row = quad*4 + reg (+i*16).
  // Atomic accumulate (4 z-chunks per address, spread in time). s==0 adds bias.
  const int row_base = m0 + wm * 64 + quad * 4;
#pragma unroll
  for (int j = 0; j < 4; ++j) {
    const int col = ncol + j * 16;
    const float bv = (s == 0) ? bias[col] : 0.0f;
#pragma unroll
    for (int i = 0; i < 4; ++i) {
      const int row = row_base + i * 16;
#pragma unroll
      for (int r = 0; r < 4; ++r)
        unsafeAtomicAdd(&out[(size_t)(row + r) * OUT_F + col], acc[i][j][r] + bv);
    }
  }
}

extern "C" void kernel_launch(void* const* d_in, const int* in_sizes, int n_in,
                              void* d_out, int out_size, void* d_ws, size_t ws_size,
                              hipStream_t stream) {
  const float* x      = (const float*)d_in[0];  // [1024][4096] fp32
  const float* cent   = (const float*)d_in[1];  // [2048][8] fp32
  const float* bias   = (const float*)d_in[2];  // [4096] fp32
  const int*   assign = (const int*)d_in[3];    // [512*4096] int32
  float* out = (float*)d_out;

  // ws layout: xs (8 MB) | centb (32 KB)   -- no partials needed (atomics)
  const size_t xb_bytes = (size_t)NTOK * IN_F * sizeof(u16);      // 8388608
  u16* xs    = (u16*)d_ws;
  u16* centb = (u16*)((char*)d_ws + xb_bytes);

  hipLaunchKernelGGL(zero_kernel, dim3((NTOK * OUT_F / 4) / 256), dim3(256), 0, stream, out);
  hipLaunchKernelGGL(cast_swz_kernel, dim3(64 * 32), dim3(256), 0, stream, x, xs);
  hipLaunchKernelGGL(cast_bf16_kernel, dim3((NCENT * 8 / 8) / 256), dim3(256), 0, stream,
                     cent, centb);
  hipLaunchKernelGGL(gemm_fused_kernel, dim3(OUT_F / 128, NTOK / 128, SPLITK), dim3(256), 0, stream,
                     xs, centb, assign, bias, out);
}

// Round 3
// 157.217 us; speedup vs baseline: 1.0094x; 1.0094x over previous
//
#include <hip/hip_runtime.h>
#include <hip/hip_bf16.h>

#define IN_F   4096
#define OUT_F  4096
#define QBLK   8
#define NBLKS  512
#define NTOK   1024
#define NCENT  2048

#define SPLITK 4
#define KCHUNK (IN_F / SPLITK)   // 1024
#define KITERS (KCHUNK / 32)     // 32

typedef unsigned int u32;
typedef unsigned short u16;
typedef __attribute__((ext_vector_type(8))) short short8;   // 8 bf16 (MFMA A/B frag)
typedef __attribute__((ext_vector_type(4))) float floatx4;  // MFMA C/D frag

// round-to-nearest-even fp32 -> bf16
__device__ __forceinline__ u16 f2bf(float f) {
  union { float f; u32 u; } v; v.f = f;
  u32 u = v.u;
  return (u16)((u + 0x7fffu + ((u >> 16) & 1u)) >> 16);
}

__device__ __forceinline__ void load_lds_16(const void* g, void* l) {
  __builtin_amdgcn_global_load_lds(
      (const __attribute__((address_space(1))) u32*)g,
      (__attribute__((address_space(3))) u32*)l, 16, 0, 0);
}

// ---------------------------------------------------------------------------
// cast fp32 -> bf16, 8 elems per thread (x and centroids, plain layout)
// ---------------------------------------------------------------------------
__global__ __launch_bounds__(256) void cast_bf16_kernel(
    const float* __restrict__ src, u16* __restrict__ dst) {
  int g = blockIdx.x * 256 + threadIdx.x;   // one 8-element chunk
  const float4* sv = (const float4*)src;
  float4 a = sv[(size_t)g * 2];
  float4 b = sv[(size_t)g * 2 + 1];
  union { u16 s[8]; uint4 v; } o;
  o.s[0] = f2bf(a.x); o.s[1] = f2bf(a.y); o.s[2] = f2bf(a.z); o.s[3] = f2bf(a.w);
  o.s[4] = f2bf(b.x); o.s[5] = f2bf(b.y); o.s[6] = f2bf(b.z); o.s[7] = f2bf(b.w);
  ((uint4*)dst)[g] = o.v;
}

// ---------------------------------------------------------------------------
// Fused GEMM: C[m][n] = sum_k x[m][k] * centroids[assign[(k/8)*OUT_F+n]][k%8]
// Block tile 128x128, 4 waves (2x2) each 64x64 (4x4 of mfma_f32_16x16x32_bf16).
// A: staged global->LDS by DMA (global_load_lds, shared by all 4 waves),
//    DOUBLE-BUFFERED with counted s_waitcnt vmcnt(4) + raw s_barrier -- one
//    barrier per K-iter and no vmcnt(0) drain (the next tile's DMA latency
//    hides under this iter's gathers+MFMA). XOR swizzle (k-quad ^= row&3)
//    on both DMA source and LDS read kills the 8-way bank conflict.
// B: fragments gathered from the read-only 32 KB bf16 centroid table in LDS
//    (one 16 B lookup per lane per frag); indices prefetched one iter ahead.
// Regs: <=128 total (64 acc AGPR + ~60 VGPR) -> 4 waves/SIMD allowed;
// LDS 48 KB -> 3 blocks/CU -> 12 waves/CU resident.
// Split-K over blockIdx.z; s=0 -> d_out, s>0 -> partials (NO atomics: R2
// showed device-scope f32 atomics write through to HBM, +25 us).
// ---------------------------------------------------------------------------
__global__ __launch_bounds__(256, 4) void gemm_fused_kernel(
    const u16* __restrict__ A,      // xb [NTOK][IN_F] bf16
    const u16* __restrict__ centb,  // [NCENT][8] bf16
    const int* __restrict__ assign, // [NBLKS*OUT_F] block-major
    const float* __restrict__ bias,
    float* __restrict__ out0,       // d_out (chunk s=0)
    float* __restrict__ partials) { // (SPLITK-1) x [NTOK][OUT_F]
  __shared__ __align__(16) u16 cs[NCENT * 8];     // 32 KB centroid table
  __shared__ __align__(16) u16 As[2][128 * 32];   // 2 x 8 KB A tile, swizzled

  const int t = threadIdx.x;
  const int lane = t & 63;
  const int wv = t >> 6;
  const int wm = wv >> 1;
  const int wn = wv & 1;
  const int quad = lane >> 4;
  const int r16 = lane & 15;
  const int m0 = blockIdx.y * 128;
  const int n0 = blockIdx.x * 128;
  const int s = blockIdx.z;
  const int kb0 = (s * KCHUNK) >> 3;       // first quant block of this chunk
  const int k_base = kb0 << 3;

  // stage centroid table: 2048 chunks of 16B = 8 per thread (DMA, no VGPR)
#pragma unroll
  for (int it = 0; it < 8; ++it) {
    int c = it * 256 + t;
    load_lds_16(centb + (size_t)c * 8, cs + (size_t)c * 8);
  }

  // stage A tile for iter 0 into As[0] (XOR-swizzled source, linear dest)
  {
    const int p0 = t;          // chunks t and 256+t
#pragma unroll
    for (int i = 0; i < 2; ++i) {
      int p = i * 256 + p0;
      int row = p >> 2;
      int q = (p & 3) ^ (row & 3);
      load_lds_16(A + (size_t)(m0 + row) * IN_F + k_base + q * 8, &As[0][p * 8]);
    }
  }

  floatx4 acc[4][4];
#pragma unroll
  for (int i = 0; i < 4; ++i)
#pragma unroll
    for (int j = 0; j < 4; ++j)
#pragma unroll
      for (int r = 0; r < 4; ++r) acc[i][j][r] = 0.0f;

  const int ncol = n0 + wn * 64 + r16;
  const int sq = quad ^ (r16 & 3);   // read-side swizzle (row&3 == r16&3)
  const int* ai = assign + (size_t)kb0 * OUT_F;   // uniform base
  const u32 vi = (u32)(quad * OUT_F + ncol);      // per-lane elem offset

  // prologue: iter-0 indices; full drain + barrier once (table + tile 0)
  int idxc[4], idxn[4];
#pragma unroll
  for (int j = 0; j < 4; ++j) idxc[j] = ai[vi + (u32)(j * 16)];
  __syncthreads();

  const short8* csv = (const short8*)cs;
  int buf = 0;

  for (int kt = 0; kt < KITERS; ++kt) {
    const bool not_last = (kt + 1 < KITERS);
    if (not_last) {
      // issue next A tile DMA FIRST (must be oldest vmem ops of this iter)
      const int k0n = k_base + (kt + 1) * 32;
#pragma unroll
      for (int i = 0; i < 2; ++i) {
        int p = i * 256 + t;
        int row = p >> 2;
        int q = (p & 3) ^ (row & 3);
        load_lds_16(A + (size_t)(m0 + row) * IN_F + k0n + q * 8,
                    &As[buf ^ 1][p * 8]);
      }
      __builtin_amdgcn_sched_barrier(0);   // pin DMA before idx loads
      // prefetch next iter's indices (register loads, stay in flight)
      const int* an = ai + (size_t)(kt + 1) * 4 * OUT_F;
#pragma unroll
      for (int j = 0; j < 4; ++j) idxn[j] = an[vi + (u32)(j * 16)];
    }

    // A fragments from LDS (swizzled), B fragments gathered from table
    const short8* Asv = (const short8*)As[buf];
    short8 af[4], bfr[4];
#pragma unroll
    for (int i = 0; i < 4; ++i)
      af[i] = Asv[(wm * 64 + i * 16 + r16) * 4 + sq];
#pragma unroll
    for (int j = 0; j < 4; ++j) bfr[j] = csv[idxc[j]];

#pragma unroll
    for (int i = 0; i < 4; ++i)
#pragma unroll
      for (int j = 0; j < 4; ++j)
        acc[i][j] = __builtin_amdgcn_mfma_f32_16x16x32_bf16(af[i], bfr[j], acc[i][j], 0, 0, 0);

#pragma unroll
    for (int j = 0; j < 4; ++j) idxc[j] = idxn[j];

    if (not_last) {
      // counted wait: outstanding = 2 DMA (oldest) + 4 idx; vmcnt(4) drains
      // only the DMA -> next buffer ready; idx loads stay in flight.
      __builtin_amdgcn_sched_barrier(0);
      asm volatile("s_waitcnt vmcnt(4)" ::: "memory");
      __builtin_amdgcn_sched_barrier(0);
      __builtin_amdgcn_s_barrier();
      __builtin_amdgcn_sched_barrier(0);
    }
    buf ^= 1;
  }

  // epilogue: C/D layout col = lane&15 (+j*16), row = quad*4 + reg (+i*16)
  float* C = (s == 0) ? out0 : (partials + (size_t)(s - 1) * NTOK * OUT_F);
  const int row_base = m0 + wm * 64 + quad * 4;
#pragma unroll
  for (int j = 0; j < 4; ++j) {
    const int col = ncol + j * 16;
    const float bv = 0.0f;  // bias folded in reduce pass
#pragma unroll
    for (int i = 0; i < 4; ++i) {
      const int row = row_base + i * 16;
#pragma unroll
      for (int r = 0; r < 4; ++r)
        C[(size_t)(row + r) * OUT_F + col] = acc[i][j][r] + bv;
    }
  }
}

// ---------------------------------------------------------------------------
// reduce: out += sum(partials) + bias   (float4 per thread)
// ---------------------------------------------------------------------------
__global__ __launch_bounds__(256) void reduce_kernel(
    float* __restrict__ out, const float* __restrict__ partials,
    const float* __restrict__ bias, int sm1) {
  int g = blockIdx.x * 256 + threadIdx.x;  // float4 index over [NTOK*OUT_F/4]
  float4 v = ((const float4*)out)[g];
  for (int s = 0; s < sm1; ++s) {
    float4 p = ((const float4*)(partials + (size_t)s * NTOK * OUT_F))[g];
    v.x += p.x; v.y += p.y; v.z += p.z; v.w += p.w;
  }
  float4 b = ((const float4*)bias)[g & (OUT_F / 4 - 1)];
  v.x += b.x; v.y += b.y; v.z += b.z; v.w += b.w;
  ((float4*)out)[g] = v;
}

extern "C" void kernel_launch(void* const* d_in, const int* in_sizes, int n_in,
                              void* d_out, int out_size, void* d_ws, size_t ws_size,
                              hipStream_t stream) {
  const float* x      = (const float*)d_in[0];  // [1024][4096] fp32
  const float* cent   = (const float*)d_in[1];  // [2048][8] fp32
  const float* bias   = (const float*)d_in[2];  // [4096] fp32
  const int*   assign = (const int*)d_in[3];    // [512*4096] int32
  float* out = (float*)d_out;

  // ws layout: xb (8 MB) | centb (32 KB) | partials (SPLITK-1)*16 MB
  const size_t xb_bytes   = (size_t)NTOK * IN_F * sizeof(u16);      // 8388608
  const size_t cent_bytes = (size_t)NCENT * 8 * sizeof(u16);        // 32768
  u16*   xb       = (u16*)d_ws;
  u16*   centb    = (u16*)((char*)d_ws + xb_bytes);
  float* partials = (float*)((char*)d_ws + xb_bytes + cent_bytes);

  hipLaunchKernelGGL(cast_bf16_kernel, dim3((NTOK * IN_F / 8) / 256), dim3(256), 0, stream,
                     x, xb);
  hipLaunchKernelGGL(cast_bf16_kernel, dim3((NCENT * 8 / 8) / 256), dim3(256), 0, stream,
                     cent, centb);
  hipLaunchKernelGGL(gemm_fused_kernel, dim3(OUT_F / 128, NTOK / 128, SPLITK), dim3(256), 0, stream,
                     xb, centb, assign, bias, out, partials);
  hipLaunchKernelGGL(reduce_kernel, dim3((NTOK * OUT_F / 4) / 256), dim3(256), 0, stream,
                     out, partials, bias, SPLITK - 1);
}

// Round 4
// 140.873 us; speedup vs baseline: 1.1265x; 1.1160x over previous
//
#include <hip/hip_runtime.h>
#include <hip/hip_bf16.h>

#define IN_F   4096
#define OUT_F  4096
#define QBLK   8
#define NBLKS  512
#define NTOK   1024
#define NCENT  2048

#define SPLITK 4
#define KCHUNK (IN_F / SPLITK)   // 1024
#define KITERS (KCHUNK / 32)     // 32

typedef unsigned int u32;
typedef unsigned short u16;
typedef __attribute__((ext_vector_type(8))) short short8;   // 8 bf16 (MFMA A/B frag)
typedef __attribute__((ext_vector_type(4))) float floatx4;  // MFMA C/D frag

// round-to-nearest-even fp32 -> bf16
__device__ __forceinline__ u16 f2bf(float f) {
  union { float f; u32 u; } v; v.f = f;
  u32 u = v.u;
  return (u16)((u + 0x7fffu + ((u >> 16) & 1u)) >> 16);
}

__device__ __forceinline__ void load_lds_16(const void* g, void* l) {
  __builtin_amdgcn_global_load_lds(
      (const __attribute__((address_space(1))) u32*)g,
      (__attribute__((address_space(3))) u32*)l, 16, 0, 0);
}

// ---------------------------------------------------------------------------
// cast fp32 -> bf16, 8 elems per thread (x and centroids, plain layout)
// ---------------------------------------------------------------------------
__global__ __launch_bounds__(256) void cast_bf16_kernel(
    const float* __restrict__ src, u16* __restrict__ dst) {
  int g = blockIdx.x * 256 + threadIdx.x;   // one 8-element chunk
  const float4* sv = (const float4*)src;
  float4 a = sv[(size_t)g * 2];
  float4 b = sv[(size_t)g * 2 + 1];
  union { u16 s[8]; uint4 v; } o;
  o.s[0] = f2bf(a.x); o.s[1] = f2bf(a.y); o.s[2] = f2bf(a.z); o.s[3] = f2bf(a.w);
  o.s[4] = f2bf(b.x); o.s[5] = f2bf(b.y); o.s[6] = f2bf(b.z); o.s[7] = f2bf(b.w);
  ((uint4*)dst)[g] = o.v;
}

// ---------------------------------------------------------------------------
// Fused GEMM: C[m][n] = sum_k x[m][k] * centroids[assign[(k/8)*OUT_F+n]][k%8]
// Block tile 128x128, 4 waves (2x2) each 64x64 (4x4 of mfma_f32_16x16x32_bf16).
// EXACTLY R0's structure with ONE change: As is double-buffered, so the DMA
// for tile kt+1 is issued at the TOP of iter kt and the single per-iter
// __syncthreads (whose implicit vmcnt(0) drain R0 paid with zero compute in
// front) now lands after a full iteration of gathers+MFMA -- DMA latency
// hidden, barrier count halved. No inline asm, no sched_barrier (R3's
// regression causes). Index loads prefetched one iter ahead in registers.
// As uses XOR swizzle (k-quad ^= row&3) on DMA source + LDS read to kill the
// 8-way bank conflict of the unpadded [128][32] layout.
// LDS 48 KB -> 3 blocks/CU (12 waves). Split-K over blockIdx.z; s=0 ->
// d_out, s>0 -> partials; bias folded in reduce.
// ---------------------------------------------------------------------------
__global__ __launch_bounds__(256, 3) void gemm_fused_kernel(
    const u16* __restrict__ A,      // xb [NTOK][IN_F] bf16
    const u16* __restrict__ centb,  // [NCENT][8] bf16
    const int* __restrict__ assign, // [NBLKS*OUT_F] block-major
    const float* __restrict__ bias,
    float* __restrict__ out0,       // d_out (chunk s=0)
    float* __restrict__ partials) { // (SPLITK-1) x [NTOK][OUT_F]
  __shared__ __align__(16) u16 cs[NCENT * 8];     // 32 KB centroid table
  __shared__ __align__(16) u16 As[2][128 * 32];   // 2 x 8 KB A tile, swizzled

  const int t = threadIdx.x;
  const int lane = t & 63;
  const int wv = t >> 6;
  const int wm = wv >> 1;
  const int wn = wv & 1;
  const int quad = lane >> 4;
  const int r16 = lane & 15;
  const int m0 = blockIdx.y * 128;
  const int n0 = blockIdx.x * 128;
  const int s = blockIdx.z;
  const int kb0 = (s * KCHUNK) >> 3;       // first quant block of this chunk
  const int k_base = kb0 << 3;

  // stage centroid table: 2048 chunks of 16B = 8 per thread (DMA, no VGPR)
#pragma unroll
  for (int it = 0; it < 8; ++it) {
    int c = it * 256 + t;
    load_lds_16(centb + (size_t)c * 8, cs + (size_t)c * 8);
  }

  // per-thread staging geometry (invariant): chunks p = t and 256+t
  // row = p>>2, swizzled quad q = (p&3) ^ (row&3)
  const int p0r = t >> 2, p0q = (t & 3) ^ (p0r & 3);
  const int p1 = 256 + t;
  const int p1r = p1 >> 2, p1q = (p1 & 3) ^ (p1r & 3);
  const u16* g0 = A + (size_t)(m0 + p0r) * IN_F + k_base + p0q * 8;
  const u16* g1 = A + (size_t)(m0 + p1r) * IN_F + k_base + p1q * 8;
  u16* l0 = &As[0][t * 8];
  u16* l1 = &As[0][p1 * 8];

  // stage A tile for iter 0 into As[0]
  load_lds_16(g0, l0);
  load_lds_16(g1, l1);

  floatx4 acc[4][4];
#pragma unroll
  for (int i = 0; i < 4; ++i)
#pragma unroll
    for (int j = 0; j < 4; ++j)
#pragma unroll
      for (int r = 0; r < 4; ++r) acc[i][j][r] = 0.0f;

  const int ncol = n0 + wn * 64 + r16;
  const int sq = quad ^ (r16 & 3);   // read-side swizzle (row&3 == r16&3)
  const int* ai = assign + (size_t)kb0 * OUT_F;   // uniform base
  const u32 vi = (u32)(quad * OUT_F + ncol);      // per-lane elem offset

  // prologue: iter-0 indices; one full-drain barrier (table + tile 0)
  int idxc[4], idxn[4];
#pragma unroll
  for (int j = 0; j < 4; ++j) idxc[j] = ai[vi + (u32)(j * 16)];
  __syncthreads();

  const short8* csv = (const short8*)cs;
  int buf = 0;

  for (int kt = 0; kt < KITERS; ++kt) {
    const bool not_last = (kt + 1 < KITERS);
    if (not_last) {
      // issue next A-tile DMA into the other buffer (drained by the barrier
      // at the END of this iteration, after gathers+MFMA hide its latency)
      const int koff = (kt + 1) * 32;                 // elements
      const int lofs = (buf ^ 1) * (128 * 32);        // u16 elements
      load_lds_16(g0 + koff, l0 + lofs);
      load_lds_16(g1 + koff, l1 + lofs);
      // prefetch next iter's indices into registers
      const int* an = ai + (size_t)(kt + 1) * 4 * OUT_F;
#pragma unroll
      for (int j = 0; j < 4; ++j) idxn[j] = an[vi + (u32)(j * 16)];
    }

    // A fragments from LDS (swizzled), B fragments gathered from table
    const short8* Asv = (const short8*)As[buf];
    short8 af[4], bfr[4];
#pragma unroll
    for (int i = 0; i < 4; ++i)
      af[i] = Asv[(wm * 64 + i * 16 + r16) * 4 + sq];
#pragma unroll
    for (int j = 0; j < 4; ++j) bfr[j] = csv[idxc[j]];

#pragma unroll
    for (int i = 0; i < 4; ++i)
#pragma unroll
      for (int j = 0; j < 4; ++j)
        acc[i][j] = __builtin_amdgcn_mfma_f32_16x16x32_bf16(af[i], bfr[j], acc[i][j], 0, 0, 0);

#pragma unroll
    for (int j = 0; j < 4; ++j) idxc[j] = idxn[j];

    if (not_last) __syncthreads();   // drains next-tile DMA; protects buffers
    buf ^= 1;
  }

  // epilogue: C/D layout col = lane&15 (+j*16), row = quad*4 + reg (+i*16)
  float* C = (s == 0) ? out0 : (partials + (size_t)(s - 1) * NTOK * OUT_F);
  const int row_base = m0 + wm * 64 + quad * 4;
#pragma unroll
  for (int j = 0; j < 4; ++j) {
    const int col = ncol + j * 16;
#pragma unroll
    for (int i = 0; i < 4; ++i) {
      const int row = row_base + i * 16;
#pragma unroll
      for (int r = 0; r < 4; ++r)
        C[(size_t)(row + r) * OUT_F + col] = acc[i][j][r];
    }
  }
}

// ---------------------------------------------------------------------------
// reduce: out += sum(partials) + bias   (float4 per thread)
// ---------------------------------------------------------------------------
__global__ __launch_bounds__(256) void reduce_kernel(
    float* __restrict__ out, const float* __restrict__ partials,
    const float* __restrict__ bias, int sm1) {
  int g = blockIdx.x * 256 + threadIdx.x;  // float4 index over [NTOK*OUT_F/4]
  float4 v = ((const float4*)out)[g];
  for (int s = 0; s < sm1; ++s) {
    float4 p = ((const float4*)(partials + (size_t)s * NTOK * OUT_F))[g];
    v.x += p.x; v.y += p.y; v.z += p.z; v.w += p.w;
  }
  float4 b = ((const float4*)bias)[g & (OUT_F / 4 - 1)];
  v.x += b.x; v.y += b.y; v.z += b.z; v.w += b.w;
  ((float4*)out)[g] = v;
}

extern "C" void kernel_launch(void* const* d_in, const int* in_sizes, int n_in,
                              void* d_out, int out_size, void* d_ws, size_t ws_size,
                              hipStream_t stream) {
  const float* x      = (const float*)d_in[0];  // [1024][4096] fp32
  const float* cent   = (const float*)d_in[1];  // [2048][8] fp32
  const float* bias   = (const float*)d_in[2];  // [4096] fp32
  const int*   assign = (const int*)d_in[3];    // [512*4096] int32
  float* out = (float*)d_out;

  // ws layout: xb (8 MB) | centb (32 KB) | partials (SPLITK-1)*16 MB
  const size_t xb_bytes   = (size_t)NTOK * IN_F * sizeof(u16);      // 8388608
  const size_t cent_bytes = (size_t)NCENT * 8 * sizeof(u16);        // 32768
  u16*   xb       = (u16*)d_ws;
  u16*   centb    = (u16*)((char*)d_ws + xb_bytes);
  float* partials = (float*)((char*)d_ws + xb_bytes + cent_bytes);

  hipLaunchKernelGGL(cast_bf16_kernel, dim3((NTOK * IN_F / 8) / 256), dim3(256), 0, stream,
                     x, xb);
  hipLaunchKernelGGL(cast_bf16_kernel, dim3((NCENT * 8 / 8) / 256), dim3(256), 0, stream,
                     cent, centb);
  hipLaunchKernelGGL(gemm_fused_kernel, dim3(OUT_F / 128, NTOK / 128, SPLITK), dim3(256), 0, stream,
                     xb, centb, assign, bias, out, partials);
  hipLaunchKernelGGL(reduce_kernel, dim3((NTOK * OUT_F / 4) / 256), dim3(256), 0, stream,
                     out, partials, bias, SPLITK - 1);
}

// Round 5
// 129.279 us; speedup vs baseline: 1.2275x; 1.0897x over previous
//
#include <hip/hip_runtime.h>
#include <hip/hip_bf16.h>

#define IN_F   4096
#define OUT_F  4096
#define QBLK   8
#define NBLKS  512
#define NTOK   1024
#define NCENT  2048

#define SPLITK 4
#define KCHUNK (IN_F / SPLITK)   // 1024
#define KITERS (KCHUNK / 32)     // 32

typedef unsigned int u32;
typedef unsigned short u16;
typedef __attribute__((ext_vector_type(8))) short short8;   // 8 bf16 (MFMA A/B frag)
typedef __attribute__((ext_vector_type(4))) float floatx4;  // MFMA C/D frag

// round-to-nearest-even fp32 -> bf16
__device__ __forceinline__ u16 f2bf(float f) {
  union { float f; u32 u; } v; v.f = f;
  u32 u = v.u;
  return (u16)((u + 0x7fffu + ((u >> 16) & 1u)) >> 16);
}

__device__ __forceinline__ void load_lds_16(const void* g, void* l) {
  __builtin_amdgcn_global_load_lds(
      (const __attribute__((address_space(1))) u32*)g,
      (__attribute__((address_space(3))) u32*)l, 16, 0, 0);
}

// ---------------------------------------------------------------------------
// cast fp32 -> bf16 (plain layout) -- used for centroids only
// ---------------------------------------------------------------------------
__global__ __launch_bounds__(256) void cast_bf16_kernel(
    const float* __restrict__ src, u16* __restrict__ dst) {
  int g = blockIdx.x * 256 + threadIdx.x;   // one 8-element chunk
  const float4* sv = (const float4*)src;
  float4 a = sv[(size_t)g * 2];
  float4 b = sv[(size_t)g * 2 + 1];
  union { u16 s[8]; uint4 v; } o;
  o.s[0] = f2bf(a.x); o.s[1] = f2bf(a.y); o.s[2] = f2bf(a.z); o.s[3] = f2bf(a.w);
  o.s[4] = f2bf(b.x); o.s[5] = f2bf(b.y); o.s[6] = f2bf(b.z); o.s[7] = f2bf(b.w);
  ((uint4*)dst)[g] = o.v;
}

// ---------------------------------------------------------------------------
// cast x fp32 -> bf16 in MFMA-fragment-ordered layout:
//   elem (m,k) -> [(m>>4)*512 + (k>>3)]*128 + (m&15)*8 + (k&7)
// A wave's A-fragment load becomes ONE contiguous 1 KB global_load_dwordx4.
// ---------------------------------------------------------------------------
__global__ __launch_bounds__(256) void cast_swz_kernel(
    const float* __restrict__ src, u16* __restrict__ dst) {
  __shared__ __align__(16) u16 ls[256 * 8];      // 256 chunks of 16 B = 4 KB
  const int b = blockIdx.x;
  const int mg = b >> 5;          // m-group 0..63
  const int kq = b & 31;          // k-chunk of 128 elems, 0..31
  const int t = threadIdx.x;
  const int ml = t >> 4;          // m within group 0..15
  const int kbl = t & 15;         // quant block within chunk 0..15

  const float* p = src + (size_t)(mg * 16 + ml) * IN_F + kq * 128 + kbl * 8;
  float4 a = ((const float4*)p)[0];
  float4 c = ((const float4*)p)[1];
  union { u16 s[8]; uint4 v; } o;
  o.s[0] = f2bf(a.x); o.s[1] = f2bf(a.y); o.s[2] = f2bf(a.z); o.s[3] = f2bf(a.w);
  o.s[4] = f2bf(c.x); o.s[5] = f2bf(c.y); o.s[6] = f2bf(c.z); o.s[7] = f2bf(c.w);

  const int cidx = (kbl << 4) | (ml ^ kbl);      // bank-spread slot
  *(uint4*)&ls[cidx * 8] = o.v;
  __syncthreads();

  const int g = (t & 0xF0) | ((t & 15) ^ ((t >> 4) & 15));
  uint4* dbase = (uint4*)(dst + (size_t)(mg * 512 + kq * 16) * 128);
  dbase[g] = ((const uint4*)ls)[t];
}

// ---------------------------------------------------------------------------
// Fused GEMM, barrier-free K-loop (exactly R2's loop), partials epilogue.
//   C[m][n] = sum_k x[m][k] * centroids[assign[(k/8)*OUT_F+n]][k%8]
// Block tile 128x128, 4 waves (2x2) each 64x64 (4x4 of mfma_f32_16x16x32_bf16).
// A fragments: direct coalesced 1KB global loads from fragment-ordered xs
// (L1-served, wm-pair reuse), register double-buffered one iter ahead.
// Addressing 32-bit: per-lane A offset and idx offset are ONE u32 each;
// uniform parts in SGPRs. Total regs (VGPR + 64 acc) <= 128 -> 4 waves/SIMD.
// B fragments: gathered from the read-only 32 KB bf16 centroid table in LDS
// (the ONLY LDS traffic in the loop: ~390 cyc/block-iter vs 644 when A is
// LDS-staged). No __syncthreads in the loop.
// Epilogue: plain stores -- s=0 -> d_out, s>0 -> partials. NO atomics (R2
// showed 64 MB of 4B device-scope RMWs write through HBM at ~1.3 TB/s).
// ---------------------------------------------------------------------------
__global__ __launch_bounds__(256, 4) void gemm_fused_kernel(
    const u16* __restrict__ xs,     // x bf16, fragment-ordered [64][512][16][8]
    const u16* __restrict__ centb,  // [NCENT][8] bf16
    const int* __restrict__ assign, // [NBLKS*OUT_F] block-major
    const float* __restrict__ bias,
    float* __restrict__ out0,       // d_out (chunk s=0)
    float* __restrict__ partials) { // (SPLITK-1) x [NTOK][OUT_F]
  __shared__ __align__(16) u16 cs[NCENT * 8];   // 32 KB centroid table

  const int t = threadIdx.x;
  const int lane = t & 63;
  const int wv = t >> 6;
  const int wm = wv >> 1;
  const int wn = wv & 1;
  const int quad = lane >> 4;
  const int r16 = lane & 15;
  const int m0 = blockIdx.y * 128;
  const int n0 = blockIdx.x * 128;
  const int s = blockIdx.z;
  const int kb0 = (s * KCHUNK) >> 3;       // first quant block of this chunk

  // stage centroid table: 2048 chunks of 16B = 8 per thread (DMA, no VGPR)
#pragma unroll
  for (int it = 0; it < 8; ++it) {
    int c = it * 256 + t;
    load_lds_16(centb + (size_t)c * 8, cs + (size_t)c * 8);
  }

  floatx4 acc[4][4];
#pragma unroll
  for (int i = 0; i < 4; ++i)
#pragma unroll
    for (int j = 0; j < 4; ++j)
#pragma unroll
      for (int r = 0; r < 4; ++r) acc[i][j][r] = 0.0f;

  const int ncol = n0 + wn * 64 + r16;

  // A: uniform base (SGPR) + one per-lane u32 byte offset.
  // short8 index was ((m>>4)*512 + kb)*16 + (m&15); in bytes x16.
  const char* xA = (const char*)xs +
      ((size_t)((m0 >> 4) + wm * 4) * 512 + kb0) * 256;  // uniform
  const u32 va = (u32)(quad * 256 + r16 * 16);           // per-lane bytes
  // idx: uniform base + one per-lane u32 element offset
  const int* ai = assign + (size_t)kb0 * OUT_F;          // uniform
  const u32 vi = (u32)(quad * OUT_F + ncol);             // per-lane elems

  // prologue: load iter-0 A frags + indices
  short8 afc[4];
  int idxc[4];
#pragma unroll
  for (int i = 0; i < 4; ++i)
    afc[i] = *(const short8*)(xA + (va + (u32)i * 131072u));
#pragma unroll
  for (int j = 0; j < 4; ++j) idxc[j] = ai[vi + (u32)(j * 16)];

  __syncthreads();   // centroid table ready (single barrier of the kernel)

  const short8* csv = (const short8*)cs;
#pragma unroll 2
  for (int kt = 0; kt < KITERS; ++kt) {
    // prefetch next iteration's A frags + indices (uniform guard)
    short8 afn[4];
    int idxn[4];
    if (kt + 1 < KITERS) {
      const char* xk = xA + (va + (u32)((kt + 1) * 1024));
#pragma unroll
      for (int i = 0; i < 4; ++i)
        afn[i] = *(const short8*)(xk + (u32)i * 131072u);
      const int* an = ai + (size_t)(kt + 1) * 4 * OUT_F;
#pragma unroll
      for (int j = 0; j < 4; ++j) idxn[j] = an[vi + (u32)(j * 16)];
    }

    // gather B frags from LDS table (one 16 B lookup per lane per frag)
    short8 bfr[4];
#pragma unroll
    for (int j = 0; j < 4; ++j) bfr[j] = csv[idxc[j]];

#pragma unroll
    for (int i = 0; i < 4; ++i)
#pragma unroll
      for (int j = 0; j < 4; ++j)
        acc[i][j] = __builtin_amdgcn_mfma_f32_16x16x32_bf16(afc[i], bfr[j], acc[i][j], 0, 0, 0);

#pragma unroll
    for (int i = 0; i < 4; ++i) afc[i] = afn[i];
#pragma unroll
    for (int j = 0; j < 4; ++j) idxc[j] = idxn[j];
  }

  // epilogue: C/D layout col = lane&15 (+j*16), row = quad*4 + reg (+i*16)
  float* C = (s == 0) ? out0 : (partials + (size_t)(s - 1) * NTOK * OUT_F);
  const int row_base = m0 + wm * 64 + quad * 4;
#pragma unroll
  for (int j = 0; j < 4; ++j) {
    const int col = ncol + j * 16;
#pragma unroll
    for (int i = 0; i < 4; ++i) {
      const int row = row_base + i * 16;
#pragma unroll
      for (int r = 0; r < 4; ++r)
        C[(size_t)(row + r) * OUT_F + col] = acc[i][j][r];
    }
  }
}

// ---------------------------------------------------------------------------
// reduce: out += sum(partials) + bias   (float4 per thread)
// ---------------------------------------------------------------------------
__global__ __launch_bounds__(256) void reduce_kernel(
    float* __restrict__ out, const float* __restrict__ partials,
    const float* __restrict__ bias, int sm1) {
  int g = blockIdx.x * 256 + threadIdx.x;  // float4 index over [NTOK*OUT_F/4]
  float4 v = ((const float4*)out)[g];
  for (int s = 0; s < sm1; ++s) {
    float4 p = ((const float4*)(partials + (size_t)s * NTOK * OUT_F))[g];
    v.x += p.x; v.y += p.y; v.z += p.z; v.w += p.w;
  }
  float4 b = ((const float4*)bias)[g & (OUT_F / 4 - 1)];
  v.x += b.x; v.y += b.y; v.z += b.z; v.w += b.w;
  ((float4*)out)[g] = v;
}

extern "C" void kernel_launch(void* const* d_in, const int* in_sizes, int n_in,
                              void* d_out, int out_size, void* d_ws, size_t ws_size,
                              hipStream_t stream) {
  const float* x      = (const float*)d_in[0];  // [1024][4096] fp32
  const float* cent   = (const float*)d_in[1];  // [2048][8] fp32
  const float* bias   = (const float*)d_in[2];  // [4096] fp32
  const int*   assign = (const int*)d_in[3];    // [512*4096] int32
  float* out = (float*)d_out;

  // ws layout: xs (8 MB) | centb (32 KB) | partials (SPLITK-1)*16 MB
  const size_t xb_bytes   = (size_t)NTOK * IN_F * sizeof(u16);      // 8388608
  const size_t cent_bytes = (size_t)NCENT * 8 * sizeof(u16);        // 32768
  u16*   xs       = (u16*)d_ws;
  u16*   centb    = (u16*)((char*)d_ws + xb_bytes);
  float* partials = (float*)((char*)d_ws + xb_bytes + cent_bytes);

  hipLaunchKernelGGL(cast_swz_kernel, dim3(64 * 32), dim3(256), 0, stream, x, xs);
  hipLaunchKernelGGL(cast_bf16_kernel, dim3((NCENT * 8 / 8) / 256), dim3(256), 0, stream,
                     cent, centb);
  hipLaunchKernelGGL(gemm_fused_kernel, dim3(OUT_F / 128, NTOK / 128, SPLITK), dim3(256), 0, stream,
                     xs, centb, assign, bias, out, partials);
  hipLaunchKernelGGL(reduce_kernel, dim3((NTOK * OUT_F / 4) / 256), dim3(256), 0, stream,
                     out, partials, bias, SPLITK - 1);
}

// Round 8
// 127.418 us; speedup vs baseline: 1.2455x; 1.0146x over previous
//
#include <hip/hip_runtime.h>
#include <hip/hip_bf16.h>

#define IN_F   4096
#define OUT_F  4096
#define QBLK   8
#define NBLKS  512
#define NTOK   1024
#define NCENT  2048

#define SPLITK 4
#define KCHUNK (IN_F / SPLITK)   // 1024
#define KITERS (KCHUNK / 32)     // 32

typedef unsigned int u32;
typedef unsigned short u16;
typedef __attribute__((ext_vector_type(8))) short short8;   // 8 bf16 (MFMA A/B frag)
typedef __attribute__((ext_vector_type(4))) float floatx4;  // MFMA C/D frag

// round-to-nearest-even fp32 -> bf16
__device__ __forceinline__ u16 f2bf(float f) {
  union { float f; u32 u; } v; v.f = f;
  u32 u = v.u;
  return (u16)((u + 0x7fffu + ((u >> 16) & 1u)) >> 16);
}

__device__ __forceinline__ void load_lds_16(const void* g, void* l) {
  __builtin_amdgcn_global_load_lds(
      (const __attribute__((address_space(1))) u32*)g,
      (__attribute__((address_space(3))) u32*)l, 16, 0, 0);
}

// ---------------------------------------------------------------------------
// cast fp32 -> bf16 (plain layout) -- used for centroids only
// ---------------------------------------------------------------------------
__global__ __launch_bounds__(256) void cast_bf16_kernel(
    const float* __restrict__ src, u16* __restrict__ dst) {
  int g = blockIdx.x * 256 + threadIdx.x;   // one 8-element chunk
  const float4* sv = (const float4*)src;
  float4 a = sv[(size_t)g * 2];
  float4 b = sv[(size_t)g * 2 + 1];
  union { u16 s[8]; uint4 v; } o;
  o.s[0] = f2bf(a.x); o.s[1] = f2bf(a.y); o.s[2] = f2bf(a.z); o.s[3] = f2bf(a.w);
  o.s[4] = f2bf(b.x); o.s[5] = f2bf(b.y); o.s[6] = f2bf(b.z); o.s[7] = f2bf(b.w);
  ((uint4*)dst)[g] = o.v;
}

// ---------------------------------------------------------------------------
// cast x fp32 -> bf16 in MFMA-fragment-ordered layout:
//   elem (m,k) -> [(m>>4)*512 + (k>>3)]*128 + (m&15)*8 + (k&7)
// A wave's A-fragment load becomes ONE contiguous 1 KB global_load_dwordx4.
// ---------------------------------------------------------------------------
__global__ __launch_bounds__(256) void cast_swz_kernel(
    const float* __restrict__ src, u16* __restrict__ dst) {
  __shared__ __align__(16) u16 ls[256 * 8];      // 256 chunks of 16 B = 4 KB
  const int b = blockIdx.x;
  const int mg = b >> 5;          // m-group 0..63
  const int kq = b & 31;          // k-chunk of 128 elems, 0..31
  const int t = threadIdx.x;
  const int ml = t >> 4;          // m within group 0..15
  const int kbl = t & 15;         // quant block within chunk 0..15

  const float* p = src + (size_t)(mg * 16 + ml) * IN_F + kq * 128 + kbl * 8;
  float4 a = ((const float4*)p)[0];
  float4 c = ((const float4*)p)[1];
  union { u16 s[8]; uint4 v; } o;
  o.s[0] = f2bf(a.x); o.s[1] = f2bf(a.y); o.s[2] = f2bf(a.z); o.s[3] = f2bf(a.w);
  o.s[4] = f2bf(c.x); o.s[5] = f2bf(c.y); o.s[6] = f2bf(c.z); o.s[7] = f2bf(c.w);

  const int cidx = (kbl << 4) | (ml ^ kbl);      // bank-spread slot
  *(uint4*)&ls[cidx * 8] = o.v;
  __syncthreads();

  const int g = (t & 0xF0) | ((t & 15) ^ ((t >> 4) & 15));
  uint4* dbase = (uint4*)(dst + (size_t)(mg * 512 + kq * 16) * 128);
  dbase[g] = ((const uint4*)ls)[t];
}

// ---------------------------------------------------------------------------
// Fused GEMM, barrier-free K-loop (R5's loop verbatim), partials epilogue,
// ONE change vs R5: XCD-AWARE BLOCK REMAP. 1-D grid of 1024; dispatch
// round-robins linear id % 8 across XCDs, so decode:
//   z = (id&7)>>1;  tile = (id>>3)*2 + (id&1);  n = tile&31, m = tile>>5
// Each split-K chunk z then owns one XCD pair whose combined 8 MB L2 holds
// that z's working set (x-slice 2 MB + assign-slice 2 MB), instead of all 4
// z-slices (16 MB) thrashing every XCD's 4 MB L2 -- cuts the 2.3x HBM
// re-fetch (37 MB -> ~17 MB) and converts ~900-cyc HBM-miss stalls (deeper
// than the 1-iter prefetch covers) into ~200-cyc L2 hits.
//   C[m][n] = sum_k x[m][k] * centroids[assign[(k/8)*OUT_F+n]][k%8]
// Block tile 128x128, 4 waves (2x2) each 64x64 (4x4 of mfma_f32_16x16x32_bf16).
// A fragments: direct coalesced 1KB global loads from fragment-ordered xs,
// register double-buffered one iter ahead; 32-bit addressing; regs <= 128
// -> 4 waves/SIMD. B: gathered from 32 KB LDS centroid table. No loop
// barriers. Epilogue: plain stores (s=0 -> out, s>0 -> partials; NO atomics).
// ---------------------------------------------------------------------------
__global__ __launch_bounds__(256, 4) void gemm_fused_kernel(
    const u16* __restrict__ xs,     // x bf16, fragment-ordered [64][512][16][8]
    const u16* __restrict__ centb,  // [NCENT][8] bf16
    const int* __restrict__ assign, // [NBLKS*OUT_F] block-major
    const float* __restrict__ bias,
    float* __restrict__ out0,       // d_out (chunk s=0)
    float* __restrict__ partials) { // (SPLITK-1) x [NTOK][OUT_F]
  __shared__ __align__(16) u16 cs[NCENT * 8];   // 32 KB centroid table

  // XCD-aware remap (bijective over 1024 blocks)
  const int id = blockIdx.x;
  const int s = (id & 7) >> 1;             // z: one XCD pair per chunk
  const int tile = ((id >> 3) << 1) | (id & 1);
  const int n0 = (tile & 31) * 128;
  const int m0 = (tile >> 5) * 128;

  const int t = threadIdx.x;
  const int lane = t & 63;
  const int wv = t >> 6;
  const int wm = wv >> 1;
  const int wn = wv & 1;
  const int quad = lane >> 4;
  const int r16 = lane & 15;
  const int kb0 = (s * KCHUNK) >> 3;       // first quant block of this chunk

  // stage centroid table: 2048 chunks of 16B = 8 per thread (DMA, no VGPR)
#pragma unroll
  for (int it = 0; it < 8; ++it) {
    int c = it * 256 + t;
    load_lds_16(centb + (size_t)c * 8, cs + (size_t)c * 8);
  }

  floatx4 acc[4][4];
#pragma unroll
  for (int i = 0; i < 4; ++i)
#pragma unroll
    for (int j = 0; j < 4; ++j)
#pragma unroll
      for (int r = 0; r < 4; ++r) acc[i][j][r] = 0.0f;

  const int ncol = n0 + wn * 64 + r16;

  // A: uniform base (SGPR) + one per-lane u32 byte offset.
  const char* xA = (const char*)xs +
      ((size_t)((m0 >> 4) + wm * 4) * 512 + kb0) * 256;  // uniform
  const u32 va = (u32)(quad * 256 + r16 * 16);           // per-lane bytes
  // idx: uniform base + one per-lane u32 element offset
  const int* ai = assign + (size_t)kb0 * OUT_F;          // uniform
  const u32 vi = (u32)(quad * OUT_F + ncol);             // per-lane elems

  // prologue: load iter-0 A frags + indices
  short8 afc[4];
  int idxc[4];
#pragma unroll
  for (int i = 0; i < 4; ++i)
    afc[i] = *(const short8*)(xA + (va + (u32)i * 131072u));
#pragma unroll
  for (int j = 0; j < 4; ++j) idxc[j] = ai[vi + (u32)(j * 16)];

  __syncthreads();   // centroid table ready (single barrier of the kernel)

  const short8* csv = (const short8*)cs;
#pragma unroll 2
  for (int kt = 0; kt < KITERS; ++kt) {
    // prefetch next iteration's A frags + indices (uniform guard)
    short8 afn[4];
    int idxn[4];
    if (kt + 1 < KITERS) {
      const char* xk = xA + (va + (u32)((kt + 1) * 1024));
#pragma unroll
      for (int i = 0; i < 4; ++i)
        afn[i] = *(const short8*)(xk + (u32)i * 131072u);
      const int* an = ai + (size_t)(kt + 1) * 4 * OUT_F;
#pragma unroll
      for (int j = 0; j < 4; ++j) idxn[j] = an[vi + (u32)(j * 16)];
    }

    // gather B frags from LDS table (one 16 B lookup per lane per frag)
    short8 bfr[4];
#pragma unroll
    for (int j = 0; j < 4; ++j) bfr[j] = csv[idxc[j]];

#pragma unroll
    for (int i = 0; i < 4; ++i)
#pragma unroll
      for (int j = 0; j < 4; ++j)
        acc[i][j] = __builtin_amdgcn_mfma_f32_16x16x32_bf16(afc[i], bfr[j], acc[i][j], 0, 0, 0);

#pragma unroll
    for (int i = 0; i < 4; ++i) afc[i] = afn[i];
#pragma unroll
    for (int j = 0; j < 4; ++j) idxc[j] = idxn[j];
  }

  // epilogue: C/D layout col = lane&15 (+j*16), row = quad*4 + reg (+i*16)
  float* C = (s == 0) ? out0 : (partials + (size_t)(s - 1) * NTOK * OUT_F);
  const int row_base = m0 + wm * 64 + quad * 4;
#pragma unroll
  for (int j = 0; j < 4; ++j) {
    const int col = ncol + j * 16;
#pragma unroll
    for (int i = 0; i < 4; ++i) {
      const int row = row_base + i * 16;
#pragma unroll
      for (int r = 0; r < 4; ++r)
        C[(size_t)(row + r) * OUT_F + col] = acc[i][j][r];
    }
  }
}

// ---------------------------------------------------------------------------
// reduce: out += sum(partials) + bias   (float4 per thread)
// ---------------------------------------------------------------------------
__global__ __launch_bounds__(256) void reduce_kernel(
    float* __restrict__ out, const float* __restrict__ partials,
    const float* __restrict__ bias, int sm1) {
  int g = blockIdx.x * 256 + threadIdx.x;  // float4 index over [NTOK*OUT_F/4]
  float4 v = ((const float4*)out)[g];
  for (int s = 0; s < sm1; ++s) {
    float4 p = ((const float4*)(partials + (size_t)s * NTOK * OUT_F))[g];
    v.x += p.x; v.y += p.y; v.z += p.z; v.w += p.w;
  }
  float4 b = ((const float4*)bias)[g & (OUT_F / 4 - 1)];
  v.x += b.x; v.y += b.y; v.z += b.z; v.w += b.w;
  ((float4*)out)[g] = v;
}

extern "C" void kernel_launch(void* const* d_in, const int* in_sizes, int n_in,
                              void* d_out, int out_size, void* d_ws, size_t ws_size,
                              hipStream_t stream) {
  const float* x      = (const float*)d_in[0];  // [1024][4096] fp32
  const float* cent   = (const float*)d_in[1];  // [2048][8] fp32
  const float* bias   = (const float*)d_in[2];  // [4096] fp32
  const int*   assign = (const int*)d_in[3];    // [512*4096] int32
  float* out = (float*)d_out;

  // ws layout: xs (8 MB) | centb (32 KB) | partials (SPLITK-1)*16 MB
  const size_t xb_bytes   = (size_t)NTOK * IN_F * sizeof(u16);      // 8388608
  const size_t cent_bytes = (size_t)NCENT * 8 * sizeof(u16);        // 32768
  u16*   xs       = (u16*)d_ws;
  u16*   centb    = (u16*)((char*)d_ws + xb_bytes);
  float* partials = (float*)((char*)d_ws + xb_bytes + cent_bytes);

  hipLaunchKernelGGL(cast_swz_kernel, dim3(64 * 32), dim3(256), 0, stream, x, xs);
  hipLaunchKernelGGL(cast_bf16_kernel, dim3((NCENT * 8 / 8) / 256), dim3(256), 0, stream,
                     cent, centb);
  hipLaunchKernelGGL(gemm_fused_kernel, dim3(1024), dim3(256), 0, stream,
                     xs, centb, assign, bias, out, partials);
  hipLaunchKernelGGL(reduce_kernel, dim3((NTOK * OUT_F / 4) / 256), dim3(256), 0, stream,
                     out, partials, bias, SPLITK - 1);
}